// Round 6
// baseline (259.342 us; speedup 1.0000x reference)
//
#include <hip/hip_runtime.h>
#include <hip/hip_bf16.h>

#define DEVFN static __device__ __forceinline__

typedef short bf16x8 __attribute__((ext_vector_type(8)));
typedef float f32x4  __attribute__((ext_vector_type(4)));

// ---------------- problem constants ----------------
constexpr int TSEQ  = 79;
constexpr int MWG   = 16;          // batch rows per WAVE
constexpr int ROWU  = 344;         // LDS row stride in bf16 (172 dwords, %32==12 -> uniform banks)
constexpr int NBLK  = 16384 / 64;  // 256 blocks x 4 waves x 16 batch

// per-layer tables. Unit map: x at unit 0; layer l h at [LO[l], LO[l]+LU[l]).
constexpr int LD[8]   = {1,64,32,16,8,16,32,64};        // input dim
constexpr int LU[8]   = {64,32,16,8,16,32,64,79};       // units
constexpr int LS[8]   = {0,8,72,104,120,128,144,176};   // input span start unit
constexpr int LO[8]   = {8,72,104,120,128,144,176,240}; // output start unit
constexpr int LKP[8]  = {96,96,64,32,32,64,96,160};     // K padded to 32
constexpr int LKS[8]  = {3,3,2,1,1,2,3,5};              // K-steps (KP/32)
constexpr int LUP[8]  = {64,32,16,16,16,32,64,80};      // padded rows in weight table
constexpr int WOFF[8] = {0,6144,9216,10240,10752,11264,13312,19456};
constexpr int WTOTAL  = 32256;                           // bf16 elems in weight table

// Depth-1 design (R12-R15): one wave owns all 8 layers for 16 batch rows.
// No barriers; LDS single-buffered h scratch per wave. Own-recurrence
// chunks are read HOISTED at timestep start (still t-1 values); fresh
// chunks (h_{l-1}(t)) read after the producer layer's writes. Stale
// cross-layer regions in a chunk hit zero-weight rows -> value-free.
// R12/R13 FAIL bit-identical, R14 FAIL with DIFFERENT absmax after adding
// fences -> UB signature. ROOT CAUSE FOUND (R15): bias tile count is
// Sum(NT)=20 but bi was declared [18] -> layer 7 tiles 3,4 hit bi[18..19]
// OOB (UB; codegen-dependent garbage C-init for output units 48..79).
// R15 fix: bi[20]. Fences kept (R14 config) — thin them next round.
constexpr int NT[8]  = {4,2,1,1,1,2,4,5};               // tiles per layer
constexpr int AO[8]  = {0,12,18,20,21,22,26,38};        // a-frag offsets (total 63)
constexpr int TO[8]  = {0,4,6,7,8,9,11,15};             // bias tile offsets (total 20)
constexpr int NH[8]  = {3,1,1,0,0,1,2,3};               // hoistable chunks per layer
constexpr int BHO[8] = {0,3,4,5,5,5,6,8};               // cumulative NH (total 11)
// chunk processing order: hoisted k's first, fresh k's last
constexpr int KORD[8][5] = {
  {0,1,2,0,0},{2,0,1,0,0},{1,0,0,0,0},{0,0,0,0,0},
  {0,0,0,0,0},{1,0,0,0,0},{1,2,0,0,0},{2,3,4,0,1}};

DEVFN unsigned short f2bf(float f) {           // RNE (setup paths only)
  unsigned int u = __builtin_bit_cast(unsigned int, f);
  return (unsigned short)((u + 0x7FFFu + ((u >> 16) & 1u)) >> 16);
}
// hot-path pack: round-half-away (u+0x8000) + single v_perm_b32.
DEVFN unsigned int pk_rna(float a, float b) {
  unsigned int ua = __builtin_bit_cast(unsigned int, a) + 0x8000u;
  unsigned int ub = __builtin_bit_cast(unsigned int, b) + 0x8000u;
  return __builtin_amdgcn_perm(ub, ua, 0x07060302u);  // [ub.b3 ub.b2 ua.b3 ua.b2]
}
DEVFN float sigmoidf(float v) {
  return __builtin_amdgcn_rcpf(1.0f + __expf(-v));
}

// full DS ordering fence: no instruction moves across (sched_barrier),
// no memory op moves across (asm memory clobber), and all outstanding
// LDS ops are hardware-complete (lgkmcnt(0)) before anything after.
DEVFN void ds_fence() {
  __builtin_amdgcn_sched_barrier(0);
  asm volatile("s_waitcnt lgkmcnt(0)" ::: "memory");
  __builtin_amdgcn_sched_barrier(0);
}

// ---------------- weight prep: fp32 -> transposed, padded bf16 table in d_ws ----------------
__global__ void __launch_bounds__(256) prep_weights(
    const float* Wx0, const float* Wh0, const float* Wx1, const float* Wh1,
    const float* Wx2, const float* Wh2, const float* Wx3, const float* Wh3,
    const float* Wx4, const float* Wh4, const float* Wx5, const float* Wh5,
    const float* Wx6, const float* Wh6, const float* Wx7, const float* Wh7,
    unsigned short* __restrict__ wt)
{
  const float* wxp[8] = {Wx0,Wx1,Wx2,Wx3,Wx4,Wx5,Wx6,Wx7};
  const float* whp[8] = {Wh0,Wh1,Wh2,Wh3,Wh4,Wh5,Wh6,Wh7};
  int idx = blockIdx.x * 256 + threadIdx.x;
  if (idx >= WTOTAL) return;
#pragma unroll
  for (int l = 0; l < 8; ++l) {
    int sz = LUP[l] * LKP[l];
    if (idx >= WOFF[l] && idx < WOFF[l] + sz) {
      int local = idx - WOFF[l];
      int j = local / LKP[l];
      int k = local - j * LKP[l];
      float v = 0.f;
      if (j < LU[l]) {
        if (l == 0) {
          if (k == 0) v = Wx0[j];
          else if (k >= 8 && k < 72) v = Wh0[(k - 8) * 64 + j];
        } else {
          if (k < LD[l]) v = wxp[l][k * LU[l] + j];
          else if (k < LD[l] + LU[l]) v = whp[l][(k - LD[l]) * LU[l] + j];
        }
      }
      wt[idx] = f2bf(v);
    }
  }
}

// ---------------- per-wave preload: ALL layers' a-frags + bias frags ----------------
DEVFN void preload_all(const unsigned short* __restrict__ wt,
                       const float* const (&bptr)[8], int lane,
                       bf16x8 (&af)[63], f32x4 (&bi)[20])
{
  const int m0 = lane & 15, quad = lane >> 4;
#pragma unroll
  for (int l = 0; l < 8; ++l) {
#pragma unroll
    for (int t = 0; t < 5; ++t) {
      if (t >= NT[l]) continue;
      const unsigned short* base = wt + WOFF[l] + (t * 16 + m0) * LKP[l];
#pragma unroll
      for (int k = 0; k < 5; ++k) {
        if (k >= LKS[l]) continue;
        af[AO[l] + t * LKS[l] + k] =
            *reinterpret_cast<const bf16x8*>(base + k * 32 + quad * 8);
      }
      const float* bp = bptr[l];
      f32x4 bv;
#pragma unroll
      for (int r = 0; r < 4; ++r) {
        int j2 = t * 16 + quad * 4 + r;
        bv[r] = (j2 < LU[l]) ? bp[j2] : 0.0f;
      }
      bi[TO[l] + t] = bv;
    }
  }
}

// ---------------- one layer within a timestep ----------------
// NOTE: rbase/wbase intentionally NOT __restrict__ — they alias hw.
template <int L, bool LAST>
DEVFN void layer(const unsigned short* rbase,   // &hw[m][quad*8]
                 unsigned short* wbase,         // &hw[m][quad*4]
                 const bf16x8 (&af)[63], const f32x4 (&bi)[20],
                 const bf16x8 (&bh)[11],
                 float* __restrict__ out, int bb, int m, int quad)
{
  constexpr int ks = LKS[L], nt = NT[L], S = LS[L], O = LO[L], u = LU[L];
  // fresh chunks: issue reads first (latency overlaps hoisted-chunk MFMAs)
  bf16x8 fr[5];
#pragma unroll
  for (int i = 0; i < 5; ++i) {
    if (i < NH[L] || i >= ks) continue;
    fr[i] = *reinterpret_cast<const bf16x8*>(rbase + S + KORD[L][i] * 32);
  }
  f32x4 acc[5];
#pragma unroll
  for (int i = 0; i < 5; ++i) {
    if (i >= ks) continue;
    bf16x8 b = (i < NH[L]) ? bh[BHO[L] + i] : fr[i];
#pragma unroll
    for (int t = 0; t < 5; ++t) {
      if (t >= nt) continue;
      acc[t] = __builtin_amdgcn_mfma_f32_16x16x32_bf16(
          af[AO[L] + t * ks + KORD[L][i]], b,
          (i == 0) ? bi[TO[L] + t] : acc[t], 0, 0, 0);
    }
  }
  // epilogue: activation + RNA pack + b64 LDS write (or global store at t=78)
#pragma unroll
  for (int t = 0; t < 5; ++t) {
    if (t >= nt) continue;
    const int jb = t * 16 + quad * 4;
    float v0 = acc[t][0], v1 = acc[t][1], v2 = acc[t][2], v3 = acc[t][3];
    if (L == 7) {
      v0 = sigmoidf(v0); v1 = sigmoidf(v1); v2 = sigmoidf(v2); v3 = sigmoidf(v3);
      if (LAST) {
        float* op = out + (size_t)(bb + m) * 79 + jb;
        if (jb + 0 < 79) op[0] = v0;
        if (jb + 1 < 79) op[1] = v1;
        if (jb + 2 < 79) op[2] = v2;
        if (jb + 3 < 79) op[3] = v3;
      } else {
        uint2 pk;
        pk.x = pk_rna(v0, v1);
        pk.y = pk_rna(v2, v3);
        *reinterpret_cast<uint2*>(wbase + O + t * 16) = pk;  // j=79 -> pad unit 319 (zero weight)
      }
    } else {
      if (jb < u) {  // guards pad rows from clobbering neighbor units
        v0 = fmaxf(v0, 0.f); v1 = fmaxf(v1, 0.f); v2 = fmaxf(v2, 0.f); v3 = fmaxf(v3, 0.f);
        uint2 pk;
        pk.x = pk_rna(v0, v1);
        pk.y = pk_rna(v2, v3);
        *reinterpret_cast<uint2*>(wbase + O + t * 16) = pk;
      }
    }
  }
}

// ---------------- one full timestep (all 8 layers), fenced ----------------
template <bool LAST>
DEVFN void timestep(int t, unsigned short (&hw)[MWG][ROWU],
                    const unsigned short (&xw)[MWG][80],
                    const bf16x8 (&af)[63], const f32x4 (&bi)[20],
                    float* __restrict__ out, int bb, int lane)
{
  const int m = lane & 15, quad = lane >> 4;
  const unsigned short* rbase = &hw[m][quad * 8];
  unsigned short* wbase = &hw[m][quad * 4];
  // stage x_t into unit 0
  if (lane < MWG) hw[lane][0] = xw[lane][t];
  ds_fence();  // x_t visible before hoisted reads
  // hoisted reads: all own-recurrence / zero-weight chunks, still holding t-1 values
  bf16x8 bh[11];
#pragma unroll
  for (int l = 0; l < 8; ++l) {
#pragma unroll
    for (int i = 0; i < 3; ++i) {
      if (i >= NH[l]) continue;
      bh[BHO[l] + i] =
          *reinterpret_cast<const bf16x8*>(rbase + LS[l] + KORD[l][i] * 32);
    }
  }
  ds_fence();  // hoisted t-1 data safely in VGPRs before ANY epilogue write
  layer<0, LAST>(rbase, wbase, af, bi, bh, out, bb, m, quad);
  ds_fence();
  layer<1, LAST>(rbase, wbase, af, bi, bh, out, bb, m, quad);
  ds_fence();
  layer<2, LAST>(rbase, wbase, af, bi, bh, out, bb, m, quad);
  ds_fence();
  layer<3, LAST>(rbase, wbase, af, bi, bh, out, bb, m, quad);
  ds_fence();
  layer<4, LAST>(rbase, wbase, af, bi, bh, out, bb, m, quad);
  ds_fence();
  layer<5, LAST>(rbase, wbase, af, bi, bh, out, bb, m, quad);
  ds_fence();
  layer<6, LAST>(rbase, wbase, af, bi, bh, out, bb, m, quad);
  ds_fence();
  layer<7, LAST>(rbase, wbase, af, bi, bh, out, bb, m, quad);
  ds_fence();  // layer-7 writes complete before next timestep's hoists
}

// ---------------- main kernel: 4 independent waves per block, no barriers ----------------
__global__ void __launch_bounds__(256)
__attribute__((amdgpu_waves_per_eu(1, 1)))
rnn_reg(const float* __restrict__ x, const unsigned short* __restrict__ wt,
        const float* b0, const float* b1, const float* b2, const float* b3,
        const float* b4, const float* b5, const float* b6, const float* b7,
        float* __restrict__ out)
{
  __shared__ __align__(16) unsigned short hb[4][MWG][ROWU];  // per-wave single-buffer h
  __shared__ __align__(4)  unsigned short xl[4][MWG][80];    // per-wave x rows, bf16
  const int tid = threadIdx.x, lane = tid & 63, wid = tid >> 6;
  const int bb = blockIdx.x * 64 + wid * MWG;
  const float* bptr[8] = {b0, b1, b2, b3, b4, b5, b6, b7};

  // zero h scratch (pad units must be 0; h(-1) = 0)
  {
    unsigned int* p = (unsigned int*)&hb[0][0][0];
    constexpr int NW = 4 * MWG * ROWU / 2;
    for (int i = tid; i < NW; i += 256) p[i] = 0;
  }
  // preload x: block's 64 rows are one contiguous span
  {
    const float* xb = x + (size_t)blockIdx.x * 64 * TSEQ;
    for (int i = tid; i < 64 * TSEQ; i += 256) {
      int r = i / TSEQ, c = i - r * TSEQ;
      xl[r >> 4][r & 15][c] = f2bf(xb[i]);
    }
  }
  bf16x8 af[63];
  f32x4  bi[20];
  preload_all(wt, bptr, lane, af, bi);
  __syncthreads();  // only barrier in the kernel: init handoff

  unsigned short (&hw)[MWG][ROWU] = hb[wid];
  const unsigned short (&xw)[MWG][80] = xl[wid];

#pragma unroll 1
  for (int t = 0; t < TSEQ - 1; ++t)
    timestep<false>(t, hw, xw, af, bi, out, bb, lane);
  timestep<true>(TSEQ - 1, hw, xw, af, bi, out, bb, lane);
}

extern "C" void kernel_launch(void* const* d_in, const int* in_sizes, int n_in,
                              void* d_out, int out_size, void* d_ws, size_t ws_size,
                              hipStream_t stream)
{
  const float* x = (const float*)d_in[0];
  const float* Wx[8]; const float* Wh[8]; const float* b[8];
  for (int i = 0; i < 8; ++i) {
    Wx[i] = (const float*)d_in[1 + 3 * i];
    Wh[i] = (const float*)d_in[2 + 3 * i];
    b[i]  = (const float*)d_in[3 + 3 * i];
  }
  unsigned short* wt = (unsigned short*)d_ws;

  prep_weights<<<(WTOTAL + 255) / 256, 256, 0, stream>>>(
      Wx[0], Wh[0], Wx[1], Wh[1], Wx[2], Wh[2], Wx[3], Wh[3],
      Wx[4], Wh[4], Wx[5], Wh[5], Wx[6], Wh[6], Wx[7], Wh[7], wt);

  rnn_reg<<<NBLK, 256, 0, stream>>>(
      x, wt, b[0], b[1], b[2], b[3], b[4], b[5], b[6], b[7], (float*)d_out);
}

// Round 7
// 243.256 us; speedup vs baseline: 1.0661x; 1.0661x over previous
//
#include <hip/hip_runtime.h>
#include <hip/hip_bf16.h>

#define DEVFN static __device__ __forceinline__

typedef short bf16x8 __attribute__((ext_vector_type(8)));
typedef float f32x4  __attribute__((ext_vector_type(4)));

// ---------------- problem constants ----------------
constexpr int TSEQ  = 79;
constexpr int MWG   = 16;          // batch rows per WAVE
constexpr int ROWU  = 344;         // LDS row stride in bf16 (172 dwords, %32==12 -> uniform banks)
constexpr int NBLK  = 16384 / 64;  // 256 blocks x 4 waves x 16 batch

// per-layer tables. Unit map: x at unit 0; layer l h at [LO[l], LO[l]+LU[l]).
constexpr int LD[8]   = {1,64,32,16,8,16,32,64};        // input dim
constexpr int LU[8]   = {64,32,16,8,16,32,64,79};       // units
constexpr int LS[8]   = {0,8,72,104,120,128,144,176};   // input span start unit
constexpr int LO[8]   = {8,72,104,120,128,144,176,240}; // output start unit
constexpr int LKP[8]  = {96,96,64,32,32,64,96,160};     // K padded to 32
constexpr int LKS[8]  = {3,3,2,1,1,2,3,5};              // K-steps (KP/32)
constexpr int LUP[8]  = {64,32,16,16,16,32,64,80};      // padded rows in weight table
constexpr int WOFF[8] = {0,6144,9216,10240,10752,11264,13312,19456};
constexpr int WTOTAL  = 32256;                           // bf16 elems in weight table

// Depth-1 design (R12-R16): one wave owns all 8 layers for 16 batch rows.
// No barriers; LDS single-buffered h scratch per wave. Own-recurrence
// chunks are read HOISTED at timestep start (still t-1 values); fresh
// chunks (h_{l-1}(t)) read after the producer layer's writes. Stale
// cross-layer regions in a chunk hit zero-weight rows -> value-free.
// History: R12/R13/R14 FAILs were ALL the bi OOB bug (Sum(NT)=20, bi[18];
// layer-7 tiles 3,4 read garbage C-init). R15 fixed it + full fences ->
// PASS at 180.6us, but 1 wave/SIMD exposes every fence drain serially
// (5485 cyc/timestep vs ~2600 expected; 9 fences block cross-layer
// overlap). R16: fences DELETED — all hazard pairs are same-array
// constant-offset aliases (compiler preserves order) + DS pipe is
// in-order within a wave (HW RAW through LDS FIFO). Discriminating
// experiment: fail -> fences load-bearing, restore sched_barrier-only.
constexpr int NT[8]  = {4,2,1,1,1,2,4,5};               // tiles per layer
constexpr int AO[8]  = {0,12,18,20,21,22,26,38};        // a-frag offsets (total 63)
constexpr int TO[8]  = {0,4,6,7,8,9,11,15};             // bias tile offsets (total 20)
constexpr int NH[8]  = {3,1,1,0,0,1,2,3};               // hoistable chunks per layer
constexpr int BHO[8] = {0,3,4,5,5,5,6,8};               // cumulative NH (total 11)
// chunk processing order: hoisted k's first, fresh k's last
constexpr int KORD[8][5] = {
  {0,1,2,0,0},{2,0,1,0,0},{1,0,0,0,0},{0,0,0,0,0},
  {0,0,0,0,0},{1,0,0,0,0},{1,2,0,0,0},{2,3,4,0,1}};

DEVFN unsigned short f2bf(float f) {           // RNE (setup paths only)
  unsigned int u = __builtin_bit_cast(unsigned int, f);
  return (unsigned short)((u + 0x7FFFu + ((u >> 16) & 1u)) >> 16);
}
// hot-path pack: round-half-away (u+0x8000) + single v_perm_b32.
DEVFN unsigned int pk_rna(float a, float b) {
  unsigned int ua = __builtin_bit_cast(unsigned int, a) + 0x8000u;
  unsigned int ub = __builtin_bit_cast(unsigned int, b) + 0x8000u;
  return __builtin_amdgcn_perm(ub, ua, 0x07060302u);  // [ub.b3 ub.b2 ua.b3 ua.b2]
}
DEVFN float sigmoidf(float v) {
  return __builtin_amdgcn_rcpf(1.0f + __expf(-v));
}

// ---------------- weight prep: fp32 -> transposed, padded bf16 table in d_ws ----------------
__global__ void __launch_bounds__(256) prep_weights(
    const float* Wx0, const float* Wh0, const float* Wx1, const float* Wh1,
    const float* Wx2, const float* Wh2, const float* Wx3, const float* Wh3,
    const float* Wx4, const float* Wh4, const float* Wx5, const float* Wh5,
    const float* Wx6, const float* Wh6, const float* Wx7, const float* Wh7,
    unsigned short* __restrict__ wt)
{
  const float* wxp[8] = {Wx0,Wx1,Wx2,Wx3,Wx4,Wx5,Wx6,Wx7};
  const float* whp[8] = {Wh0,Wh1,Wh2,Wh3,Wh4,Wh5,Wh6,Wh7};
  int idx = blockIdx.x * 256 + threadIdx.x;
  if (idx >= WTOTAL) return;
#pragma unroll
  for (int l = 0; l < 8; ++l) {
    int sz = LUP[l] * LKP[l];
    if (idx >= WOFF[l] && idx < WOFF[l] + sz) {
      int local = idx - WOFF[l];
      int j = local / LKP[l];
      int k = local - j * LKP[l];
      float v = 0.f;
      if (j < LU[l]) {
        if (l == 0) {
          if (k == 0) v = Wx0[j];
          else if (k >= 8 && k < 72) v = Wh0[(k - 8) * 64 + j];
        } else {
          if (k < LD[l]) v = wxp[l][k * LU[l] + j];
          else if (k < LD[l] + LU[l]) v = whp[l][(k - LD[l]) * LU[l] + j];
        }
      }
      wt[idx] = f2bf(v);
    }
  }
}

// ---------------- per-wave preload: ALL layers' a-frags + bias frags ----------------
DEVFN void preload_all(const unsigned short* __restrict__ wt,
                       const float* const (&bptr)[8], int lane,
                       bf16x8 (&af)[63], f32x4 (&bi)[20])
{
  const int m0 = lane & 15, quad = lane >> 4;
#pragma unroll
  for (int l = 0; l < 8; ++l) {
#pragma unroll
    for (int t = 0; t < 5; ++t) {
      if (t >= NT[l]) continue;
      const unsigned short* base = wt + WOFF[l] + (t * 16 + m0) * LKP[l];
#pragma unroll
      for (int k = 0; k < 5; ++k) {
        if (k >= LKS[l]) continue;
        af[AO[l] + t * LKS[l] + k] =
            *reinterpret_cast<const bf16x8*>(base + k * 32 + quad * 8);
      }
      const float* bp = bptr[l];
      f32x4 bv;
#pragma unroll
      for (int r = 0; r < 4; ++r) {
        int j2 = t * 16 + quad * 4 + r;
        bv[r] = (j2 < LU[l]) ? bp[j2] : 0.0f;
      }
      bi[TO[l] + t] = bv;
    }
  }
}

// ---------------- one layer within a timestep ----------------
// NOTE: rbase/wbase intentionally NOT __restrict__ — they alias hw.
template <int L, bool LAST>
DEVFN void layer(const unsigned short* rbase,   // &hw[m][quad*8]
                 unsigned short* wbase,         // &hw[m][quad*4]
                 const bf16x8 (&af)[63], const f32x4 (&bi)[20],
                 const bf16x8 (&bh)[11],
                 float* __restrict__ out, int bb, int m, int quad)
{
  constexpr int ks = LKS[L], nt = NT[L], S = LS[L], O = LO[L], u = LU[L];
  // fresh chunks: issue reads first (latency overlaps hoisted-chunk MFMAs)
  bf16x8 fr[5];
#pragma unroll
  for (int i = 0; i < 5; ++i) {
    if (i < NH[L] || i >= ks) continue;
    fr[i] = *reinterpret_cast<const bf16x8*>(rbase + S + KORD[L][i] * 32);
  }
  f32x4 acc[5];
#pragma unroll
  for (int i = 0; i < 5; ++i) {
    if (i >= ks) continue;
    bf16x8 b = (i < NH[L]) ? bh[BHO[L] + i] : fr[i];
#pragma unroll
    for (int t = 0; t < 5; ++t) {
      if (t >= nt) continue;
      acc[t] = __builtin_amdgcn_mfma_f32_16x16x32_bf16(
          af[AO[L] + t * ks + KORD[L][i]], b,
          (i == 0) ? bi[TO[L] + t] : acc[t], 0, 0, 0);
    }
  }
  // epilogue: activation + RNA pack + b64 LDS write (or global store at t=78)
#pragma unroll
  for (int t = 0; t < 5; ++t) {
    if (t >= nt) continue;
    const int jb = t * 16 + quad * 4;
    float v0 = acc[t][0], v1 = acc[t][1], v2 = acc[t][2], v3 = acc[t][3];
    if (L == 7) {
      v0 = sigmoidf(v0); v1 = sigmoidf(v1); v2 = sigmoidf(v2); v3 = sigmoidf(v3);
      if (LAST) {
        float* op = out + (size_t)(bb + m) * 79 + jb;
        if (jb + 0 < 79) op[0] = v0;
        if (jb + 1 < 79) op[1] = v1;
        if (jb + 2 < 79) op[2] = v2;
        if (jb + 3 < 79) op[3] = v3;
      } else {
        uint2 pk;
        pk.x = pk_rna(v0, v1);
        pk.y = pk_rna(v2, v3);
        *reinterpret_cast<uint2*>(wbase + O + t * 16) = pk;  // j=79 -> pad unit 319 (zero weight)
      }
    } else {
      if (jb < u) {  // guards pad rows from clobbering neighbor units
        v0 = fmaxf(v0, 0.f); v1 = fmaxf(v1, 0.f); v2 = fmaxf(v2, 0.f); v3 = fmaxf(v3, 0.f);
        uint2 pk;
        pk.x = pk_rna(v0, v1);
        pk.y = pk_rna(v2, v3);
        *reinterpret_cast<uint2*>(wbase + O + t * 16) = pk;
      }
    }
  }
}

// ---------------- one full timestep (all 8 layers), fence-free ----------------
template <bool LAST>
DEVFN void timestep(int t, unsigned short (&hw)[MWG][ROWU],
                    const unsigned short (&xw)[MWG][80],
                    const bf16x8 (&af)[63], const f32x4 (&bi)[20],
                    float* __restrict__ out, int bb, int lane)
{
  const int m = lane & 15, quad = lane >> 4;
  const unsigned short* rbase = &hw[m][quad * 8];
  unsigned short* wbase = &hw[m][quad * 4];
  // stage x_t into unit 0 (in-order DS pipe: later reads see it)
  if (lane < MWG) hw[lane][0] = xw[lane][t];
  // hoisted reads: all own-recurrence / zero-weight chunks, still holding t-1 values.
  // Anti-dependence vs later epilogue writes (same array, overlapping constant
  // offsets) keeps these ahead of any overwrite.
  bf16x8 bh[11];
#pragma unroll
  for (int l = 0; l < 8; ++l) {
#pragma unroll
    for (int i = 0; i < 3; ++i) {
      if (i >= NH[l]) continue;
      bh[BHO[l] + i] =
          *reinterpret_cast<const bf16x8*>(rbase + LS[l] + KORD[l][i] * 32);
    }
  }
  layer<0, LAST>(rbase, wbase, af, bi, bh, out, bb, m, quad);
  layer<1, LAST>(rbase, wbase, af, bi, bh, out, bb, m, quad);
  layer<2, LAST>(rbase, wbase, af, bi, bh, out, bb, m, quad);
  layer<3, LAST>(rbase, wbase, af, bi, bh, out, bb, m, quad);
  layer<4, LAST>(rbase, wbase, af, bi, bh, out, bb, m, quad);
  layer<5, LAST>(rbase, wbase, af, bi, bh, out, bb, m, quad);
  layer<6, LAST>(rbase, wbase, af, bi, bh, out, bb, m, quad);
  layer<7, LAST>(rbase, wbase, af, bi, bh, out, bb, m, quad);
}

// ---------------- main kernel: 4 independent waves per block, no barriers ----------------
__global__ void __launch_bounds__(256)
__attribute__((amdgpu_waves_per_eu(1, 1)))
rnn_reg(const float* __restrict__ x, const unsigned short* __restrict__ wt,
        const float* b0, const float* b1, const float* b2, const float* b3,
        const float* b4, const float* b5, const float* b6, const float* b7,
        float* __restrict__ out)
{
  __shared__ __align__(16) unsigned short hb[4][MWG][ROWU];  // per-wave single-buffer h
  __shared__ __align__(4)  unsigned short xl[4][MWG][80];    // per-wave x rows, bf16
  const int tid = threadIdx.x, lane = tid & 63, wid = tid >> 6;
  const int bb = blockIdx.x * 64 + wid * MWG;
  const float* bptr[8] = {b0, b1, b2, b3, b4, b5, b6, b7};

  // zero h scratch (pad units must be 0; h(-1) = 0)
  {
    unsigned int* p = (unsigned int*)&hb[0][0][0];
    constexpr int NW = 4 * MWG * ROWU / 2;
    for (int i = tid; i < NW; i += 256) p[i] = 0;
  }
  // preload x: block's 64 rows are one contiguous span
  {
    const float* xb = x + (size_t)blockIdx.x * 64 * TSEQ;
    for (int i = tid; i < 64 * TSEQ; i += 256) {
      int r = i / TSEQ, c = i - r * TSEQ;
      xl[r >> 4][r & 15][c] = f2bf(xb[i]);
    }
  }
  bf16x8 af[63];
  f32x4  bi[20];
  preload_all(wt, bptr, lane, af, bi);
  __syncthreads();  // only barrier in the kernel: init handoff

  unsigned short (&hw)[MWG][ROWU] = hb[wid];
  const unsigned short (&xw)[MWG][80] = xl[wid];

#pragma unroll 1
  for (int t = 0; t < TSEQ - 1; ++t)
    timestep<false>(t, hw, xw, af, bi, out, bb, lane);
  timestep<true>(TSEQ - 1, hw, xw, af, bi, out, bb, lane);
}

extern "C" void kernel_launch(void* const* d_in, const int* in_sizes, int n_in,
                              void* d_out, int out_size, void* d_ws, size_t ws_size,
                              hipStream_t stream)
{
  const float* x = (const float*)d_in[0];
  const float* Wx[8]; const float* Wh[8]; const float* b[8];
  for (int i = 0; i < 8; ++i) {
    Wx[i] = (const float*)d_in[1 + 3 * i];
    Wh[i] = (const float*)d_in[2 + 3 * i];
    b[i]  = (const float*)d_in[3 + 3 * i];
  }
  unsigned short* wt = (unsigned short*)d_ws;

  prep_weights<<<(WTOTAL + 255) / 256, 256, 0, stream>>>(
      Wx[0], Wh[0], Wx[1], Wh[1], Wx[2], Wh[2], Wx[3], Wh[3],
      Wx[4], Wh[4], Wx[5], Wh[5], Wx[6], Wh[6], Wx[7], Wh[7], wt);

  rnn_reg<<<NBLK, 256, 0, stream>>>(
      x, wt, b[0], b[1], b[2], b[3], b[4], b[5], b[6], b[7], (float*)d_out);
}